// Round 3
// baseline (19570.613 us; speedup 1.0000x reference)
//
#include <hip/hip_runtime.h>

// ---------------------------------------------------------------------------
// R-Net forward on MI355X. fp32, round 3: fwd+bwd chains PAIRED in one WG so
// every weight/attT/Hmem fetch serves two chains (same bytes, 2x work, 2x ILP);
// gru_rec batches 4 b per WG; Hmem transposed to per-b contiguous [b][q][d].
//   P=256, Q=48, B=16, H=128, D=556, 2H=256, 3H=384, 4H=512
// ---------------------------------------------------------------------------

#define PP 256
#define QQ 48
#define BB 16

__device__ __forceinline__ float fast_rcp(float x) { return __builtin_amdgcn_rcpf(x); }
__device__ __forceinline__ float tanh_f(float x) {
  float e = __expf(2.0f * x);
  return 1.0f - 2.0f * fast_rcp(1.0f + e);
}
__device__ __forceinline__ float sigm_f(float x) {
  return fast_rcp(1.0f + __expf(-x));
}

// ---------------------------------------------------------------------------
// Generic C[M,N] = A[M,K] @ W[N,K]^T + bias.  64x64 tiles, BK=16, 256 thr.
// ---------------------------------------------------------------------------
__global__ __launch_bounds__(256) void gemm_nt(
    const float* __restrict__ A, int lda,
    const float* __restrict__ W, int ldw,
    const float* __restrict__ bias,
    float* __restrict__ C, int ldc, int K) {
  __shared__ float As[64][17];
  __shared__ float Ws[64][17];
  int tid = threadIdx.x;
  int m0 = blockIdx.x * 64, n0 = blockIdx.y * 64;
  int lr = tid >> 2, lq = (tid & 3) * 4;
  int tr = tid >> 4, tc = tid & 15;
  float acc[4][4] = {};
  for (int k0 = 0; k0 < K; k0 += 16) {
    float4 av = {0,0,0,0}, wv = {0,0,0,0};
    if (k0 + lq < K) {
      av = *(const float4*)&A[(size_t)(m0 + lr) * lda + k0 + lq];
      wv = *(const float4*)&W[(size_t)(n0 + lr) * ldw + k0 + lq];
    }
    __syncthreads();
    As[lr][lq+0] = av.x; As[lr][lq+1] = av.y; As[lr][lq+2] = av.z; As[lr][lq+3] = av.w;
    Ws[lr][lq+0] = wv.x; Ws[lr][lq+1] = wv.y; Ws[lr][lq+2] = wv.z; Ws[lr][lq+3] = wv.w;
    __syncthreads();
#pragma unroll
    for (int kk = 0; kk < 16; ++kk) {
      float a4[4], b4[4];
#pragma unroll
      for (int i = 0; i < 4; ++i) a4[i] = As[tr*4+i][kk];
#pragma unroll
      for (int j = 0; j < 4; ++j) b4[j] = Ws[tc*4+j][kk];
#pragma unroll
      for (int i = 0; i < 4; ++i)
#pragma unroll
        for (int j = 0; j < 4; ++j) acc[i][j] += a4[i] * b4[j];
    }
  }
#pragma unroll
  for (int i = 0; i < 4; ++i) {
    int m = m0 + tr*4 + i;
#pragma unroll
    for (int j = 0; j < 4; ++j) {
      int n = n0 + tc*4 + j;
      C[(size_t)m * ldc + n] = acc[i][j] + (bias ? bias[n] : 0.0f);
    }
  }
}

// ---------------------------------------------------------------------------
// Batched weight transposes: dst[c*R + r] = src[r*ld + off + c]
// ---------------------------------------------------------------------------
struct TDesc { const float* src; float* dst; int R, C, ld, off; };
struct TDescs { TDesc d[16]; };

__global__ __launch_bounds__(256) void transpose_many(TDescs ds) {
  TDesc d = ds.d[blockIdx.y];
  int idx = blockIdx.x * 256 + threadIdx.x;
  if (idx < d.R * d.C) {
    int r = idx / d.C, cc = idx % d.C;
    d.dst[(size_t)cc * d.R + r] = d.src[(size_t)r * d.ld + d.off + cc];
  }
}

__global__ __launch_bounds__(256) void transpose_one(
    const float* __restrict__ src, float* __restrict__ dst, int R, int C) {
  int idx = blockIdx.x * 256 + threadIdx.x;
  if (idx < R * C) {
    int r = idx / C, cc = idx % C;
    dst[(size_t)cc * R + r] = src[(size_t)r * C + cc];
  }
}

// [T,16,256] -> [16,T,256]
__global__ __launch_bounds__(256) void permute_tbd(
    const float* __restrict__ src, float* __restrict__ dst, int T) {
  int t = blockIdx.x, b = blockIdx.y, d = threadIdx.x;
  dst[((size_t)(b*T + t))*256 + d] = src[((size_t)(t*BB + b))*256 + d];
}

// ---------------------------------------------------------------------------
// GRU recurrence. 16 WGs: {p,q} x {fwd,bwd} x 4 b-groups (4 batch each).
// Each weight float4 loaded once, used for 4 batch elements (16 FMA/load).
// ---------------------------------------------------------------------------
__global__ __launch_bounds__(256) void gru_rec(
    const float* __restrict__ gi_p, const float* __restrict__ gi_q,
    const float* __restrict__ WhhT,  // [128][384] k-major
    const float* __restrict__ bhh,   // [384]
    float* __restrict__ out_p, float* __restrict__ out_q,
    float* __restrict__ Hp, float* __restrict__ Hq,
    int mode0, int finalmode) {
  int x = blockIdx.x;
  int seq = x >> 3, dir = (x >> 2) & 1, bg = x & 3;
  int T = seq ? QQ : PP;
  const float* gi = seq ? gi_q : gi_p;
  float* out = seq ? out_q : out_p;
  float* Hf  = seq ? Hq   : Hp;
  int b0 = bg * 4;
  int tid = threadIdx.x;
  __shared__ float hs[4][128];
  __shared__ float gpart[2][4][384];   // [ksplit][bb][col]
  ((float*)hs)[tid] = 0.0f;
  ((float*)hs)[256 + tid] = 0.0f;
  __syncthreads();
  int ks = tid / 96;            // k-split half (tid<192)
  int jq = (tid % 96) * 4;      // col quad
  for (int t = 0; t < T; ++t) {
    if (tid < 192) {  // partial gh = h @ Whh^T for 4 batch elements per load
      float a[4][4] = {};
      const float* wp = WhhT + (size_t)ks*64*384 + jq;
      const int kb = ks*64;
#pragma unroll 8
      for (int k = 0; k < 64; ++k) {
        float4 wv = *(const float4*)&wp[(size_t)k*384];
#pragma unroll
        for (int bb = 0; bb < 4; ++bb) {
          float hv = hs[bb][kb + k];
          a[bb][0] += hv*wv.x; a[bb][1] += hv*wv.y; a[bb][2] += hv*wv.z; a[bb][3] += hv*wv.w;
        }
      }
#pragma unroll
      for (int bb = 0; bb < 4; ++bb) {
        gpart[ks][bb][jq+0]=a[bb][0]; gpart[ks][bb][jq+1]=a[bb][1];
        gpart[ks][bb][jq+2]=a[bb][2]; gpart[ks][bb][jq+3]=a[bb][3];
      }
    }
    __syncthreads();
#pragma unroll
    for (int bb2 = 0; bb2 < 2; ++bb2) {
      int gb = (tid >> 7)*2 + bb2;
      int gj = tid & 127;
      size_t base;
      if (mode0) {
        int girow = dir ? (T-1-t) : t;
        base = ((size_t)girow*BB + b0+gb)*384;
      } else {
        base = (((size_t)dir*T + t)*BB + b0+gb)*384;
      }
      float ghr = bhh[gj]     + gpart[0][gb][gj]     + gpart[1][gb][gj];
      float ghz = bhh[128+gj] + gpart[0][gb][128+gj] + gpart[1][gb][128+gj];
      float ghn = bhh[256+gj] + gpart[0][gb][256+gj] + gpart[1][gb][256+gj];
      float gr = gi[base + gj], gz = gi[base + 128 + gj], gn = gi[base + 256 + gj];
      float r = sigm_f(gr + ghr);
      float z = sigm_f(gz + ghz);
      float n = tanh_f(gn + r * ghn);
      float h2 = (1.0f - z) * n + z * hs[gb][gj];
      hs[gb][gj] = h2;
      if (finalmode) {
        int orow = dir ? (T-1-t) : t;
        Hf[((size_t)orow*BB + b0+gb)*256 + dir*128 + gj] = h2;
      } else {
        out[(((size_t)dir*T + t)*BB + b0+gb)*128 + gj] = h2;
      }
    }
    __syncthreads();
  }
}

// ---------------------------------------------------------------------------
// Gated additive-attention LSTM: fwd AND bwd chains of one batch element in
// ONE workgroup (weights + attT[b] + Hmem[b] fetched once, used twice).
// 16 WGs, 512 threads, T=256 steps, 8 barriers/step.
// ---------------------------------------------------------------------------
__global__ __launch_bounds__(512) void attn_rec(
    const float* __restrict__ Hseq,   // [256,16,256]
    const float* __restrict__ HmemT,  // [16,Qm,256]  per-b contiguous
    const float* __restrict__ attT,   // [16,128,Qm]
    const float* __restrict__ Xcur,   // [256,16,128]
    const float* __restrict__ Xg,     // [256,16,512]
    const float* __restrict__ watt,   // [128]
    const float* __restrict__ WhidT,  // [128][128]
    const float* __restrict__ WgwT,   // [256][512]
    const float* __restrict__ WihT,   // [512][512]
    const float* __restrict__ WhhT,   // [128][512]
    const float* __restrict__ bias,   // [512]
    float* __restrict__ Hy,           // [256,16,256]
    int Qm) {
  int b = blockIdx.x;
  int tid = threadIdx.x;
  __shared__ float h[2][128], c[2][128], xh[2][128], wa[128];
  __shared__ float pe[2][256], zx[2][256], zg[2][512];
  __shared__ float pA[2][2][128];
  __shared__ float pB[2][512];
  __shared__ float pD[2][2][256];
  __shared__ float pE[2][4][512];
  __shared__ float pG[2][4][512];
  __shared__ float red[2];
  if (tid < 128) {
    h[0][tid]=0.f; h[1][tid]=0.f; c[0][tid]=0.f; c[1][tid]=0.f; wa[tid]=watt[tid];
  }
  const int QP  = (Qm == QQ) ? 64 : 256;   // padded mem length (pow2)
  const int HS  = 512 / QP;                // h-slices in score stage
  const int hl  = 128 / HS;
  const int hsh = (Qm == QQ) ? 6 : 8;      // log2(QP)
  const float* attb = attT  + (size_t)b*128*Qm;
  const float* memb = HmemT + (size_t)b*Qm*256;
  __syncthreads();
  for (int t = 0; t < PP; ++t) {
    int rf = t, rb = PP-1-t;
    {  // Stage A: hW partials (per-chain 2-way k-split) + xh/zx loads
      int ch = tid >> 8, kh = (tid >> 7) & 1, j = tid & 127;
      float acc = 0.0f;
      const float* wp = WhidT + (size_t)kh*64*128 + j;
      const float* hp = &h[ch][kh*64];
#pragma unroll 16
      for (int k = 0; k < 64; ++k) acc += hp[k] * wp[(size_t)k*128];
      pA[ch][kh][j] = acc;
      if (tid < 128)       xh[0][tid]     = Xcur[((size_t)rf*BB + b)*128 + tid];
      else if (tid < 256)  xh[1][tid-128] = Xcur[((size_t)rb*BB + b)*128 + (tid-128)];
      else if (tid < 320)  *(float4*)&zx[0][(tid-256)*4] = *(const float4*)&Hseq[((size_t)rf*BB + b)*256 + (tid-256)*4];
      else if (tid < 384)  *(float4*)&zx[1][(tid-320)*4] = *(const float4*)&Hseq[((size_t)rb*BB + b)*256 + (tid-320)*4];
    }
    __syncthreads();
    {  // Stage B: scores, BOTH chains per att load
      int q = tid & (QP-1), hh = tid >> hsh;
      float af = 0.0f, ab = 0.0f;
      if (q < Qm) {
        const float* ap = attb + q;
        int h0 = hh * hl;
#pragma unroll 8
        for (int i = 0; i < hl; ++i) {
          int hx = h0 + i;
          float av = ap[(size_t)hx*Qm];
          float xf = xh[0][hx] + pA[0][0][hx] + pA[0][1][hx];
          float xb = xh[1][hx] + pA[1][0][hx] + pA[1][1][hx];
          float wv = wa[hx];
          af += wv * tanh_f(av + xf);
          ab += wv * tanh_f(av + xb);
        }
      }
      pB[0][hh*QP + q] = af;
      pB[1][hh*QP + q] = ab;
    }
    __syncthreads();
    if (tid < 128) {  // Stage C: combine, exp, sum — one wave per chain
      int ch = tid >> 6, lane = tid & 63;
      float lsum = 0.0f;
      for (int q2 = lane; q2 < QP; q2 += 64) {
        float s = 0.0f;
        for (int i = 0; i < HS; ++i) s += pB[ch][i*QP + q2];
        float e = (q2 < Qm) ? __expf(s) : 0.0f;
        pe[ch][q2] = e; lsum += e;
      }
#pragma unroll
      for (int off = 32; off; off >>= 1) lsum += __shfl_down(lsum, off);
      if (lane == 0) red[ch] = lsum;
    }
    __syncthreads();
    {  // Stage D: w numerator partials, BOTH chains per Hmem load (q-split 2)
      int d = tid & 255, qh = tid >> 8;
      int half = Qm >> 1;
      float af = 0.0f, ab = 0.0f;
      const float* mp = memb + (size_t)(qh*half)*256 + d;
      const float* pf = &pe[0][qh*half];
      const float* pb = &pe[1][qh*half];
#pragma unroll 8
      for (int q2 = 0; q2 < half; ++q2) {
        float m = mp[(size_t)q2*256];
        af += pf[q2] * m; ab += pb[q2] * m;
      }
      pD[0][qh][d] = af; pD[1][qh][d] = ab;
    }
    __syncthreads();
    {  // Stage E: u = w @ WgwT, BOTH chains per weight load (k-split 4)
      int jq = tid & 127, kh = tid >> 7;
      float invf = fast_rcp(red[0]), invb = fast_rcp(red[1]);
      float f0=0,f1=0,f2=0,f3=0, g0=0,g1=0,g2=0,g3=0;
      const float* wp = WgwT + (size_t)kh*64*512 + jq*4;
      int k0 = kh*64;
#pragma unroll 8
      for (int k = 0; k < 64; ++k) {
        float wkf = (pD[0][0][k0+k] + pD[0][1][k0+k]) * invf;
        float wkb = (pD[1][0][k0+k] + pD[1][1][k0+k]) * invb;
        float4 wv = *(const float4*)&wp[(size_t)k*512];
        f0 += wkf*wv.x; f1 += wkf*wv.y; f2 += wkf*wv.z; f3 += wkf*wv.w;
        g0 += wkb*wv.x; g1 += wkb*wv.y; g2 += wkb*wv.z; g3 += wkb*wv.w;
      }
      pE[0][kh][jq*4+0]=f0; pE[0][kh][jq*4+1]=f1; pE[0][kh][jq*4+2]=f2; pE[0][kh][jq*4+3]=f3;
      pE[1][kh][jq*4+0]=g0; pE[1][kh][jq*4+1]=g1; pE[1][kh][jq*4+2]=g2; pE[1][kh][jq*4+3]=g3;
    }
    __syncthreads();
    {  // Stage F: gated input zg, both chains
      float uf = pE[0][0][tid]+pE[0][1][tid]+pE[0][2][tid]+pE[0][3][tid];
      float ub = pE[1][0][tid]+pE[1][1][tid]+pE[1][2][tid]+pE[1][3][tid];
      float prf = Xg[((size_t)rf*BB + b)*512 + tid] + uf;
      float prb = Xg[((size_t)rb*BB + b)*512 + tid] + ub;
      float zf, zb;
      if (tid < 256) { zf = zx[0][tid]; zb = zx[1][tid]; }
      else {
        int k = tid - 256;
        zf = (pD[0][0][k] + pD[0][1][k]) * fast_rcp(red[0]);
        zb = (pD[1][0][k] + pD[1][1][k]) * fast_rcp(red[1]);
      }
      zg[0][tid] = zf * sigm_f(prf);
      zg[1][tid] = zb * sigm_f(prb);
    }
    __syncthreads();
    {  // Stage G: gates = zg @ Wih^T + h @ Whh^T, BOTH chains per weight load
      int jq = tid & 127, kh = tid >> 7;
      float f0=0,f1=0,f2=0,f3=0, g0=0,g1=0,g2=0,g3=0;
      const float* wp = WihT + (size_t)kh*128*512 + jq*4;
      const float* zf = &zg[0][kh*128];
      const float* zb = &zg[1][kh*128];
#pragma unroll 16
      for (int k = 0; k < 128; ++k) {
        float4 wv = *(const float4*)&wp[(size_t)k*512];
        float a = zf[k], d2 = zb[k];
        f0 += a*wv.x; f1 += a*wv.y; f2 += a*wv.z; f3 += a*wv.w;
        g0 += d2*wv.x; g1 += d2*wv.y; g2 += d2*wv.z; g3 += d2*wv.w;
      }
      const float* wp2 = WhhT + (size_t)kh*32*512 + jq*4;
      const float* hf = &h[0][kh*32];
      const float* hb = &h[1][kh*32];
#pragma unroll
      for (int k = 0; k < 32; ++k) {
        float4 wv = *(const float4*)&wp2[(size_t)k*512];
        float a = hf[k], d2 = hb[k];
        f0 += a*wv.x; f1 += a*wv.y; f2 += a*wv.z; f3 += a*wv.w;
        g0 += d2*wv.x; g1 += d2*wv.y; g2 += d2*wv.z; g3 += d2*wv.w;
      }
      pG[0][kh][jq*4+0]=f0; pG[0][kh][jq*4+1]=f1; pG[0][kh][jq*4+2]=f2; pG[0][kh][jq*4+3]=f3;
      pG[1][kh][jq*4+0]=g0; pG[1][kh][jq*4+1]=g1; pG[1][kh][jq*4+2]=g2; pG[1][kh][jq*4+3]=g3;
    }
    __syncthreads();
    if (tid < 256) {  // Stage H: LSTM cell, both chains (gate order i,f,g,o)
      int ch = tid >> 7, j = tid & 127;
      int row = ch ? rb : rf;
      float gi_ = bias[j]     + pG[ch][0][j]     + pG[ch][1][j]     + pG[ch][2][j]     + pG[ch][3][j];
      float gf_ = bias[128+j] + pG[ch][0][128+j] + pG[ch][1][128+j] + pG[ch][2][128+j] + pG[ch][3][128+j];
      float gg_ = bias[256+j] + pG[ch][0][256+j] + pG[ch][1][256+j] + pG[ch][2][256+j] + pG[ch][3][256+j];
      float go_ = bias[384+j] + pG[ch][0][384+j] + pG[ch][1][384+j] + pG[ch][2][384+j] + pG[ch][3][384+j];
      float ii = sigm_f(gi_), ff = sigm_f(gf_), gg = tanh_f(gg_), oo = sigm_f(go_);
      float cn = ff * c[ch][j] + ii * gg;
      float hn = oo * tanh_f(cn);
      c[ch][j] = cn; h[ch][j] = hn;
      Hy[((size_t)row*BB + b)*256 + ch*128 + j] = hn;
    }
    __syncthreads();
  }
}

// ---------------------------------------------------------------------------
// Answer pointer network. 16 WGs (one per batch element), 256 threads, 2 steps.
// ---------------------------------------------------------------------------
__global__ __launch_bounds__(256) void ptr_net(
    const float* __restrict__ Hq,    // [48,16,256]
    const float* __restrict__ Hs,    // [256,16,256]
    const float* __restrict__ attp,  // [256,16,128] = Hs@Wal^T
    const float* __restrict__ WaaT,  // [128][128]
    const float* __restrict__ wbeta, // [128]
    const float* __restrict__ WahT,  // [256][128]
    const float* __restrict__ bah,
    const float* __restrict__ WacT,
    const float* __restrict__ bac,
    const float* __restrict__ WihT,  // [256][512]
    const float* __restrict__ WhhT,  // [128][512]
    const float* __restrict__ bptr,  // [512]
    float* __restrict__ out) {       // [2,256,16]
  int b = blockIdx.x;
  int tid = threadIdx.x;
  __shared__ float qp[256], h[128], c[128], haa[128], pe2[256], wv[256], part[1024];
  __shared__ float red[1];
  {
    float acc = 0.0f;
#pragma unroll 8
    for (int q = 0; q < QQ; ++q) acc += Hq[((size_t)q*BB + b)*256 + tid];
    qp[tid] = acc * (1.0f/48.0f);
  }
  __syncthreads();
  if (tid < 128) {
    float ah = bah[tid], ac = bac[tid];
#pragma unroll 8
    for (int k = 0; k < 256; ++k) {
      ah += qp[k] * WahT[k*128 + tid];
      ac += qp[k] * WacT[k*128 + tid];
    }
    h[tid] = ah; c[tid] = ac;
  }
  __syncthreads();
  for (int step = 0; step < 2; ++step) {
    if (tid < 128) {
      float acc = 0.0f;
#pragma unroll 8
      for (int k = 0; k < 128; ++k) acc += h[k] * WaaT[k*128 + tid];
      haa[tid] = acc;
    }
    __syncthreads();
    {
      const float* ap = attp + (size_t)tid*BB*128 + b*128;
      float s = 0.0f;
#pragma unroll 8
      for (int k = 0; k < 128; ++k) s += wbeta[k] * tanh_f(ap[k] + haa[k]);
      pe2[tid] = __expf(s);
    }
    __syncthreads();
    if (tid < 64) {
      float s2 = pe2[tid] + pe2[tid+64] + pe2[tid+128] + pe2[tid+192];
#pragma unroll
      for (int off = 32; off; off >>= 1) s2 += __shfl_down(s2, off);
      if (tid == 0) red[0] = s2;
    }
    __syncthreads();
    float inv = fast_rcp(red[0]);
    out[((size_t)step*PP + tid)*BB + b] = pe2[tid] * inv;
    {
      float acc = 0.0f;
#pragma unroll 8
      for (int p2 = 0; p2 < PP; ++p2) acc += pe2[p2] * Hs[((size_t)p2*BB + b)*256 + tid];
      wv[tid] = acc * inv;
    }
    __syncthreads();
    {
      int jq = tid & 127, kh = tid >> 7;
      float a0=0,a1=0,a2=0,a3=0;
      const float* wp = WihT + (size_t)kh*128*512 + jq*4;
      const float* vp = &wv[kh*128];
#pragma unroll 16
      for (int k = 0; k < 128; ++k) {
        float4 w4 = *(const float4*)&wp[(size_t)k*512];
        float v = vp[k];
        a0 += v*w4.x; a1 += v*w4.y; a2 += v*w4.z; a3 += v*w4.w;
      }
      const float* wp2 = WhhT + (size_t)kh*64*512 + jq*4;
      const float* hp = &h[kh*64];
#pragma unroll
      for (int k = 0; k < 64; ++k) {
        float4 w4 = *(const float4*)&wp2[(size_t)k*512];
        float v = hp[k];
        a0 += v*w4.x; a1 += v*w4.y; a2 += v*w4.z; a3 += v*w4.w;
      }
      part[kh*512 + jq*4 + 0] = a0; part[kh*512 + jq*4 + 1] = a1;
      part[kh*512 + jq*4 + 2] = a2; part[kh*512 + jq*4 + 3] = a3;
    }
    __syncthreads();
    if (tid < 128) {
      float gii = bptr[tid]     + part[tid]     + part[512+tid];
      float gff = bptr[128+tid] + part[128+tid] + part[640+tid];
      float ggg = bptr[256+tid] + part[256+tid] + part[768+tid];
      float goo = bptr[384+tid] + part[384+tid] + part[896+tid];
      float ii = sigm_f(gii), ff = sigm_f(gff), gg = tanh_f(ggg), oo = sigm_f(goo);
      float cn = ff * c[tid] + ii * gg;
      h[tid] = oo * tanh_f(cn); c[tid] = cn;
    }
    __syncthreads();
  }
}

// ---------------------------------------------------------------------------
extern "C" void kernel_launch(void* const* d_in, const int* in_sizes, int n_in,
                              void* d_out, int out_size, void* d_ws, size_t ws_size,
                              hipStream_t stream) {
  const float* p_inp  = (const float*)d_in[0];
  const float* q_inp  = (const float*)d_in[1];
  const float* g0_Wih = (const float*)d_in[2];
  const float* g0_Whh = (const float*)d_in[3];
  const float* g0_bih = (const float*)d_in[4];
  const float* g0_bhh = (const float*)d_in[5];
  const float* g1_Wih = (const float*)d_in[6];
  const float* g1_Whh = (const float*)d_in[7];
  const float* g1_bih = (const float*)d_in[8];
  const float* g1_bhh = (const float*)d_in[9];
  const float* g2_Wih = (const float*)d_in[10];
  const float* g2_Whh = (const float*)d_in[11];
  const float* g2_bih = (const float*)d_in[12];
  const float* g2_bhh = (const float*)d_in[13];
  const float* Wq     = (const float*)d_in[14];
  const float* Wp     = (const float*)d_in[15];
  const float* Wh     = (const float*)d_in[16];
  const float* w_alpha= (const float*)d_in[17];
  const float* Wg_m   = (const float*)d_in[18];
  const float* m_Wih  = (const float*)d_in[19];
  const float* m_Whh  = (const float*)d_in[20];
  const float* m_b    = (const float*)d_in[21];
  const float* Wsp    = (const float*)d_in[22];
  const float* Wsh    = (const float*)d_in[23];
  const float* w_gamma= (const float*)d_in[24];
  const float* Wg_s   = (const float*)d_in[25];
  const float* s_Wih  = (const float*)d_in[26];
  const float* s_Whh  = (const float*)d_in[27];
  const float* s_b    = (const float*)d_in[28];
  const float* Wal    = (const float*)d_in[29];
  const float* Waa    = (const float*)d_in[30];
  const float* w_beta = (const float*)d_in[31];
  const float* Wah    = (const float*)d_in[32];
  const float* bah    = (const float*)d_in[33];
  const float* Wac    = (const float*)d_in[34];
  const float* bac    = (const float*)d_in[35];
  const float* pt_Wih = (const float*)d_in[36];
  const float* pt_Whh = (const float*)d_in[37];
  const float* pt_b   = (const float*)d_in[38];

  float* ws = (float*)d_ws;
  size_t o = 0;
  auto alloc = [&](size_t n) { float* p = ws + o; o += n; return p; };
  float* g0WhhT = alloc(49152);
  float* g1WhhT = alloc(49152);
  float* g2WhhT = alloc(49152);
  float* WhT    = alloc(16384);
  float* WgmWT  = alloc(131072);
  float* mWihT  = alloc(262144);
  float* mWhhT  = alloc(65536);
  float* WshT   = alloc(16384);
  float* WgsWT  = alloc(131072);
  float* sWihT  = alloc(262144);
  float* sWhhT  = alloc(65536);
  float* WaaT   = alloc(16384);
  float* WahT   = alloc(32768);
  float* WacT   = alloc(32768);
  float* ptWihT = alloc(131072);
  float* ptWhhT = alloc(65536);
  float* Hp  = alloc(1048576);   // [256,16,256]
  float* Hq_ = alloc(196608);    // [48,16,256]
  float* Hr  = alloc(1048576);
  float* Hs_ = alloc(1048576);
  float* A = alloc(6225920);
  // GRU views
  float* gi_p = A;                 // [2,256,16,384] (layer0 uses [256,16,384])
  float* gi_q = A + 3145728;       // [2,48,16,384]
  float* hA_p = A + 3735552;       // [2,256,16,128]
  float* hB_p = A + 4784128;
  float* hA_q = A + 5832704;       // [2,48,16,128]
  float* hB_q = A + 6029312;
  // match views
  float* attq  = A;                // [48,16,128]
  float* attqT = A + 98304;        // [16,128,48]
  float* Xp    = A + 196608;       // [256,16,128]
  float* XgM   = A + 720896;       // [256,16,512]
  float* HqT   = A + 2818048;      // [16,48,256]
  // self views
  float* attsp  = A;               // [256,16,128]
  float* attspT = A + 524288;      // [16,128,256]
  float* XgS    = A + 1048576;     // [256,16,512]
  float* HrT    = A + 3145728;     // [16,256,256]
  // pointer view
  float* attp = A;                 // [256,16,128]

  TDescs tds;
  tds.d[0]  = { g0_Whh, g0WhhT, 384, 128, 128, 0 };
  tds.d[1]  = { g1_Whh, g1WhhT, 384, 128, 128, 0 };
  tds.d[2]  = { g2_Whh, g2WhhT, 384, 128, 128, 0 };
  tds.d[3]  = { Wh,     WhT,    128, 128, 128, 0 };
  tds.d[4]  = { Wg_m,   WgmWT,  512, 256, 512, 256 };
  tds.d[5]  = { m_Wih,  mWihT,  512, 512, 512, 0 };
  tds.d[6]  = { m_Whh,  mWhhT,  512, 128, 128, 0 };
  tds.d[7]  = { Wsh,    WshT,   128, 128, 128, 0 };
  tds.d[8]  = { Wg_s,   WgsWT,  512, 256, 512, 256 };
  tds.d[9]  = { s_Wih,  sWihT,  512, 512, 512, 0 };
  tds.d[10] = { s_Whh,  sWhhT,  512, 128, 128, 0 };
  tds.d[11] = { Waa,    WaaT,   128, 128, 128, 0 };
  tds.d[12] = { Wah,    WahT,   128, 256, 256, 0 };
  tds.d[13] = { Wac,    WacT,   128, 256, 256, 0 };
  tds.d[14] = { pt_Wih, ptWihT, 512, 256, 256, 0 };
  tds.d[15] = { pt_Whh, ptWhhT, 512, 128, 128, 0 };
  transpose_many<<<dim3(1024, 16), 256, 0, stream>>>(tds);

  // GRU encoder
  gemm_nt<<<dim3(64, 6),  256, 0, stream>>>(p_inp, 556, g0_Wih, 556, g0_bih, gi_p, 384, 556);
  gemm_nt<<<dim3(12, 6),  256, 0, stream>>>(q_inp, 556, g0_Wih, 556, g0_bih, gi_q, 384, 556);
  gru_rec<<<16, 256, 0, stream>>>(gi_p, gi_q, g0WhhT, g0_bhh, hA_p, hA_q, nullptr, nullptr, 1, 0);
  gemm_nt<<<dim3(128, 6), 256, 0, stream>>>(hA_p, 128, g1_Wih, 128, g1_bih, gi_p, 384, 128);
  gemm_nt<<<dim3(24, 6),  256, 0, stream>>>(hA_q, 128, g1_Wih, 128, g1_bih, gi_q, 384, 128);
  gru_rec<<<16, 256, 0, stream>>>(gi_p, gi_q, g1WhhT, g1_bhh, hB_p, hB_q, nullptr, nullptr, 0, 0);
  gemm_nt<<<dim3(128, 6), 256, 0, stream>>>(hB_p, 128, g2_Wih, 128, g2_bih, gi_p, 384, 128);
  gemm_nt<<<dim3(24, 6),  256, 0, stream>>>(hB_q, 128, g2_Wih, 128, g2_bih, gi_q, 384, 128);
  gru_rec<<<16, 256, 0, stream>>>(gi_p, gi_q, g2WhhT, g2_bhh, hA_p, hA_q, Hp, Hq_, 0, 1);

  // match-LSTM
  gemm_nt<<<dim3(12, 2), 256, 0, stream>>>(Hq_, 256, Wq, 256, nullptr, attq, 128, 256);
  transpose_one<<<dim3(384), 256, 0, stream>>>(attq, attqT, 48, 2048);
  gemm_nt<<<dim3(64, 2), 256, 0, stream>>>(Hp, 256, Wp, 256, nullptr, Xp, 128, 256);
  gemm_nt<<<dim3(64, 8), 256, 0, stream>>>(Hp, 256, Wg_m, 512, nullptr, XgM, 512, 256);
  permute_tbd<<<dim3(48, 16), 256, 0, stream>>>(Hq_, HqT, 48);
  attn_rec<<<16, 512, 0, stream>>>(Hp, HqT, attqT, Xp, XgM, w_alpha, WhT, WgmWT,
                                   mWihT, mWhhT, m_b, Hr, QQ);

  // self-matching
  gemm_nt<<<dim3(64, 2), 256, 0, stream>>>(Hr, 256, Wsp, 256, nullptr, attsp, 128, 256);
  transpose_one<<<dim3(2048), 256, 0, stream>>>(attsp, attspT, 256, 2048);
  gemm_nt<<<dim3(64, 8), 256, 0, stream>>>(Hr, 256, Wg_s, 512, nullptr, XgS, 512, 256);
  permute_tbd<<<dim3(256, 16), 256, 0, stream>>>(Hr, HrT, 256);
  attn_rec<<<16, 512, 0, stream>>>(Hr, HrT, attspT, attsp, XgS, w_gamma, WshT, WgsWT,
                                   sWihT, sWhhT, s_b, Hs_, PP);

  // pointer network
  gemm_nt<<<dim3(64, 2), 256, 0, stream>>>(Hs_, 256, Wal, 256, nullptr, attp, 128, 256);
  ptr_net<<<16, 256, 0, stream>>>(Hq_, Hs_, attp, WaaT, w_beta, WahT, bah, WacT, bac,
                                  ptWihT, ptWhhT, pt_b, (float*)d_out);
}